// Round 7
// baseline (304.717 us; speedup 1.0000x reference)
//
#include <hip/hip_runtime.h>

// Problem constants (match reference)
#define Tn 4
#define Bn 512
#define Gn 16
#define Nn 256               // Gn*Gn
#define Dn 32
#define NBLK ((Tn - 1) * Bn) // 1536 blocks
#define CW 9                 // uint2 stride/cell in f16 tiles (18 uints: odd*2 -> b64 conflict-free)

#define THRESH_C 0.5f
#define EPS_POOL 1e-6f
#define ZCMW 5.0f
#define NEGBIG -1e30f

typedef unsigned int uint_t;
typedef __attribute__((ext_vector_type(2))) unsigned short u16x2;
// exact half-pair type used by the amdgcn builtins (avoids _Float16/__fp16 mismatch)
using h2 = decltype(__builtin_amdgcn_cvt_pkrtz(0.0f, 0.0f));

__device__ __forceinline__ h2 u2h(uint_t u) { return __builtin_bit_cast(h2, u); }
__device__ __forceinline__ uint_t pk_f16(float lo, float hi) {
    return __builtin_bit_cast(uint_t, __builtin_amdgcn_cvt_pkrtz(lo, hi)); // v_cvt_pkrtz_f16_f32
}
// packed max, valid for NON-NEGATIVE f16 pairs (f16 order == u16 order on >=0)
__device__ __forceinline__ uint_t pkmax(uint_t a, uint_t b) {
    u16x2 r = __builtin_elementwise_max(__builtin_bit_cast(u16x2, a),
                                        __builtin_bit_cast(u16x2, b));
    return __builtin_bit_cast(uint_t, r);
}
// dot of two f16 pairs, f32 accumulate
#if __has_builtin(__builtin_amdgcn_fdot2)
__device__ __forceinline__ float fdot2(uint_t a, uint_t b, float c) {
    return __builtin_amdgcn_fdot2(u2h(a), u2h(b), c, false);
}
#else
__device__ __forceinline__ float fdot2(uint_t a, uint_t b, float c) {
    h2 ha = u2h(a), hb = u2h(b);
    return c + (float)ha.x * (float)hb.x + (float)ha.y * (float)hb.y;
}
#endif
// DPP row ops: row of 16 lanes == one grid row. bound_ctrl=1 -> 0-fill at row edge.
__device__ __forceinline__ uint_t dpp_shr1(uint_t v) {  // lane j gets lane j-1 (0 at j=0)
    return (uint_t)__builtin_amdgcn_update_dpp(0, (int)v, 0x111, 0xF, 0xF, true);
}
__device__ __forceinline__ uint_t dpp_shl1(uint_t v) {  // lane j gets lane j+1 (0 at j=15)
    return (uint_t)__builtin_amdgcn_update_dpp(0, (int)v, 0x101, 0xF, 0xF, true);
}

// ws: partials[5][NBLK] floats, then unsigned ctr.
// k: 0=z_what_loss 1=z_pres_loss 2=pool_loss 3=objects_loss 4=n_obj
__global__ __launch_bounds__(256, 4) void fused_losses(
    const float* __restrict__ z_what,
    const float* __restrict__ z_pres_prob,
    const float* __restrict__ z_pres,
    const float* __restrict__ base_losses,
    const int* __restrict__ gstep,
    float* __restrict__ partials,
    unsigned* __restrict__ ctr,
    float* __restrict__ out)
{
    __shared__ uint2 s_z1[Nn * CW];   // z_what[t+1] packed f16 pairs (18 uints/cell)
    __shared__ uint2 s_rm[Nn * CW];   // row-max of e=|z0|*p0, packed f16
    __shared__ float s_p1[Nn];
    __shared__ float s_rn1[Nn];       // 1/max(||z1||,1e-5)
    __shared__ float s_red[4 * 5];
    __shared__ int s_last;

    const int tid  = threadIdx.x;     // cell 0..255
    const int lane = tid & 63;
    const int wave = tid >> 6;
    const int t = blockIdx.x >> 9;    // Bn = 512
    const int b = blockIdx.x & (Bn - 1);

    const size_t cb0 = ((size_t)t * Bn + b) * Nn;
    const size_t cb1 = cb0 + (size_t)Bn * Nn;

    const float p0 = z_pres_prob[cb0 + tid];
    const float p1 = z_pres_prob[cb1 + tid];

    const float4* g0 = (const float4*)(z_what + (cb0 + tid) * Dn);
    const float4* g1 = (const float4*)(z_what + (cb1 + tid) * Dn);

    // ---- load own cell (8 float4 each tensor); pack a0, z1, e=|a0|*p0 to f16 pairs
    uint_t pa0[16], pz1[16], pe[16];
    float zwl_acc = 0.f, n0sq = 0.f, n1sq = 0.f;
    #pragma unroll
    for (int k = 0; k < 8; ++k) {
        float4 v0 = g0[k], v1 = g1[k];
        float d0 = v1.x - v0.x, d1 = v1.y - v0.y, d2 = v1.z - v0.z, d3 = v1.w - v0.w;
        zwl_acc += d0 * d0 + d1 * d1 + d2 * d2 + d3 * d3;
        n0sq += v0.x * v0.x + v0.y * v0.y + v0.z * v0.z + v0.w * v0.w;
        n1sq += v1.x * v1.x + v1.y * v1.y + v1.z * v1.z + v1.w * v1.w;
        pa0[2 * k]     = pk_f16(v0.x, v0.y);
        pa0[2 * k + 1] = pk_f16(v0.z, v0.w);
        pz1[2 * k]     = pk_f16(v1.x, v1.y);
        pz1[2 * k + 1] = pk_f16(v1.z, v1.w);
        pe[2 * k]      = pk_f16(fabsf(v0.x) * p0, fabsf(v0.y) * p0);
        pe[2 * k + 1]  = pk_f16(fabsf(v0.z) * p0, fabsf(v0.w) * p0);
    }
    const float inv_n0 = 1.0f / fmaxf(sqrtf(n0sq), 1e-5f);

    // ---- row-max of e via DPP (row16 == grid row; 0-fill at edges OK since e>=0)
    uint_t rm[16];
    #pragma unroll
    for (int q = 0; q < 16; ++q)
        rm[q] = pkmax(pkmax(pe[q], dpp_shr1(pe[q])), dpp_shl1(pe[q]));

    // ---- stage tiles (b64, conflict-free stride)
    uint2* myz = &s_z1[tid * CW];
    uint2* myr = &s_rm[tid * CW];
    #pragma unroll
    for (int q = 0; q < 8; ++q) {
        myz[q] = make_uint2(pz1[2 * q], pz1[2 * q + 1]);
        myr[q] = make_uint2(rm[2 * q], rm[2 * q + 1]);
    }
    s_p1[tid] = p1;
    s_rn1[tid] = 1.0f / fmaxf(sqrtf(n1sq), 1e-5f);
    __syncthreads();   // single main-body barrier

    const int i = tid >> 4, j = tid & 15;

    // ---- pool: col-max (edges clamp to own: max(x,x)=x) + cosine vs |z1|*p1
    float dp0 = 0.f, dp1 = 0.f, na0 = 0.f, na1 = 0.f;
    {
        const uint2* ub = &s_rm[((i > 0)  ? tid - Gn : tid) * CW];
        const uint2* db = &s_rm[((i < 15) ? tid + Gn : tid) * CW];
        #pragma unroll
        for (int q = 0; q < 8; ++q) {
            uint2 u = ub[q], d = db[q];
            uint_t m0 = pkmax(pkmax(rm[2 * q],     u.x), d.x);
            uint_t m1 = pkmax(pkmax(rm[2 * q + 1], u.y), d.y);
            dp0 = fdot2(m0, pz1[2 * q]     & 0x7FFF7FFFu, dp0);
            dp1 = fdot2(m1, pz1[2 * q + 1] & 0x7FFF7FFFu, dp1);
            na0 = fdot2(m0, m0, na0);
            na1 = fdot2(m1, m1, na1);
        }
    }
    const float dotp = (dp0 + dp1) * p1;
    const float nasq = na0 + na1;
    const float nbsq = n1sq * p1 * p1;          // exact ||(|z1|*p1)||^2
    float cosv = dotp / fmaxf(sqrtf(nasq) * sqrtf(nbsq), EPS_POOL);
    float pool_acc = -cosv * 0.5f * (p0 + p1);

    // ---- objects_loss: 9 wrapped neighbors (jnp.roll)
    float sum_sim = 0.f, max_sim = NEGBIG;
    bool anym = false;
    #pragma unroll
    for (int di = -1; di <= 1; ++di) {
        #pragma unroll
        for (int dj = -1; dj <= 1; ++dj) {
            const int nb = (((i + di) & 15) << 4) | ((j + dj) & 15);
            const uint2* zz = &s_z1[nb * CW];
            float a = 0.f, c = 0.f;
            #pragma unroll
            for (int q = 0; q < 8; ++q) {
                uint2 z = zz[q];
                a = fdot2(pa0[2 * q],     z.x, a);
                c = fdot2(pa0[2 * q + 1], z.y, c);
            }
            float s = (a + c) * inv_n0 * s_rn1[nb];
            bool m = s_p1[nb] > THRESH_C;
            sum_sim += m ? s : 0.f;
            max_sim = fmaxf(max_sim, m ? s : NEGBIG);
            anym = anym || m;
        }
    }
    const bool det = p0 > THRESH_C;
    float obj_acc = (det && anym) ? (sum_sim - ZCMW * max_sim) : 0.f;
    float cnt = det ? 1.f : 0.f;

    // ---- z_pres_loss (t index covered by blocks with t < T-2)
    float zpl_acc = 0.f;
    if (t < Tn - 2) {
        const size_t zi = cb0 + tid;
        float q0 = z_pres[zi];
        float q1 = z_pres[zi + (size_t)Bn * Nn];
        float q2 = z_pres[zi + 2 * (size_t)Bn * Nn];
        float sim = 1.f - (q2 - q0) * (q2 - q0);
        zpl_acc = sim * ((q2 - q1) * (q2 - q1) + (q0 - q1) * (q0 - q1));
    }

    // ---- block reduction: wave shuffle -> LDS (4 waves)
    float vals[5] = { zwl_acc, zpl_acc, pool_acc, obj_acc, cnt };
    #pragma unroll
    for (int k = 0; k < 5; ++k) {
        float v = vals[k];
        #pragma unroll
        for (int off = 32; off; off >>= 1) v += __shfl_down(v, off);
        if (lane == 0) s_red[wave * 5 + k] = v;
    }
    __syncthreads();

    if (tid == 0) {
        #pragma unroll
        for (int k = 0; k < 5; ++k) {
            float v = s_red[k] + s_red[5 + k] + s_red[10 + k] + s_red[15 + k];
            partials[k * NBLK + blockIdx.x] = v;
        }
        __threadfence();                    // release partials
        unsigned prev = atomicAdd(ctr, 1u); // device-scope
        s_last = (prev == NBLK - 1) ? 1 : 0;
    }
    __syncthreads();

    // ---- last block reduces all partials and finalizes (no 2nd launch)
    if (s_last) {
        __threadfence();                    // acquire
        float acc[5] = { 0.f, 0.f, 0.f, 0.f, 0.f };
        for (int idx = tid; idx < NBLK; idx += 256) {
            #pragma unroll
            for (int k = 0; k < 5; ++k) acc[k] += partials[k * NBLK + idx];
        }
        #pragma unroll
        for (int k = 0; k < 5; ++k) {
            float v = acc[k];
            #pragma unroll
            for (int off = 32; off; off >>= 1) v += __shfl_down(v, off);
            if (lane == 0) s_red[wave * 5 + k] = v;
        }
        __syncthreads();
        if (tid == 0) {
            float r[5];
            #pragma unroll
            for (int k = 0; k < 5; ++k)
                r[k] = s_red[k] + s_red[5 + k] + s_red[10 + k] + s_red[15 + k];
            float bl = base_losses[0] + base_losses[1] + base_losses[2] + base_losses[3];
            float scaling = fminf(1.0f, (float)gstep[0] / 300000.0f);
            out[0] = bl + r[0] * 10.0f + r[1] + r[2] + r[3] * scaling * 10.0f;
            out[1] = r[0];
            out[2] = r[1];
            out[3] = r[2];
            out[4] = r[3];
            out[5] = r[4];
        }
    }
}

extern "C" void kernel_launch(void* const* d_in, const int* in_sizes, int n_in,
                              void* d_out, int out_size, void* d_ws, size_t ws_size,
                              hipStream_t stream) {
    const float* z_what      = (const float*)d_in[0];
    const float* z_pres_prob = (const float*)d_in[1];
    const float* z_pres      = (const float*)d_in[2];
    const float* base_losses = (const float*)d_in[3];
    const int*   gstep       = (const int*)d_in[4];

    float* partials = (float*)d_ws;                       // 5*NBLK floats
    unsigned* ctr   = (unsigned*)(partials + 5 * NBLK);   // 4 bytes

    (void)hipMemsetAsync(ctr, 0, sizeof(unsigned), stream);
    fused_losses<<<dim3(NBLK), dim3(256), 0, stream>>>(
        z_what, z_pres_prob, z_pres, base_losses, gstep,
        partials, ctr, (float*)d_out);
}

// Round 8
// 167.316 us; speedup vs baseline: 1.8212x; 1.8212x over previous
//
#include <hip/hip_runtime.h>

// Problem constants (match reference)
#define Tn 4
#define Bn 512
#define Gn 16
#define Nn 256               // Gn*Gn
#define Dn 32
#define NBLK ((Tn - 1) * Bn) // 1536 blocks
#define CW 9                 // uint2 stride/cell in f16 tiles (measured: 0 bank conflicts)

#define THRESH_C 0.5f
#define EPS_POOL 1e-6f
#define ZCMW 5.0f
#define NEGBIG -1e30f

typedef unsigned int uint_t;
typedef __attribute__((ext_vector_type(2))) unsigned short u16x2;
// exact half-pair type of the amdgcn builtins (avoids _Float16/__fp16 mismatch)
using h2 = decltype(__builtin_amdgcn_cvt_pkrtz(0.0f, 0.0f));

__device__ __forceinline__ h2 u2h(uint_t u) { return __builtin_bit_cast(h2, u); }
__device__ __forceinline__ uint_t pk_f16(float lo, float hi) {
    return __builtin_bit_cast(uint_t, __builtin_amdgcn_cvt_pkrtz(lo, hi)); // v_cvt_pkrtz_f16_f32
}
// packed max, valid for NON-NEGATIVE f16 pairs (f16 order == u16 order on >=0)
__device__ __forceinline__ uint_t pkmax(uint_t a, uint_t b) {
    u16x2 r = __builtin_elementwise_max(__builtin_bit_cast(u16x2, a),
                                        __builtin_bit_cast(u16x2, b));
    return __builtin_bit_cast(uint_t, r);
}
// dot of two f16 pairs, f32 accumulate
#if __has_builtin(__builtin_amdgcn_fdot2)
__device__ __forceinline__ float fdot2(uint_t a, uint_t b, float c) {
    return __builtin_amdgcn_fdot2(u2h(a), u2h(b), c, false);
}
#else
__device__ __forceinline__ float fdot2(uint_t a, uint_t b, float c) {
    h2 ha = u2h(a), hb = u2h(b);
    return c + (float)ha.x * (float)hb.x + (float)ha.y * (float)hb.y;
}
#endif

// ws: partials[5][NBLK] floats, then unsigned ctr.
// k: 0=z_what_loss 1=z_pres_loss 2=pool_loss 3=objects_loss 4=n_obj
__global__ __launch_bounds__(512, 6) void fused_losses(
    const float* __restrict__ z_what,
    const float* __restrict__ z_pres_prob,
    const float* __restrict__ z_pres,
    const float* __restrict__ base_losses,
    const int* __restrict__ gstep,
    float* __restrict__ partials,
    unsigned* __restrict__ ctr,
    float* __restrict__ out)
{
    __shared__ uint2 s_z1[Nn * CW];   // z_what[t+1] packed f16 pairs
    __shared__ uint2 s_buf[Nn * CW];  // overlay: e=|z0|*p0, then row-max(e)
    __shared__ float s_p1[Nn];
    __shared__ float s_rn1[Nn];       // 1/max(||z1||,1e-5)
    __shared__ float s_red[8 * 5];
    __shared__ int s_last;

    const int tid  = threadIdx.x;     // 0..511
    const int cell = tid >> 1;        // 0..255
    const int half = tid & 1;         // which 16 dims
    const int lane = tid & 63;
    const int wave = tid >> 6;
    const int t = blockIdx.x >> 9;    // Bn = 512
    const int b = blockIdx.x & (Bn - 1);

    const size_t cb0 = ((size_t)t * Bn + b) * Nn;
    const size_t cb1 = cb0 + (size_t)Bn * Nn;

    const float p0 = z_pres_prob[cb0 + cell];
    const float p1 = z_pres_prob[cb1 + cell];

    const float4* g0 = (const float4*)(z_what + (cb0 + cell) * Dn + half * 16);
    const float4* g1 = (const float4*)(z_what + (cb1 + cell) * Dn + half * 16);

    // ---- load own 16 dims (4 float4 per tensor); pack a0, z1, e=|a0|*p0
    uint_t pa0[8], pz1[8], pe[8];
    float zwl_acc = 0.f, n0sq = 0.f, n1sq = 0.f;
    #pragma unroll
    for (int k = 0; k < 4; ++k) {
        float4 v0 = g0[k], v1 = g1[k];
        float d0 = v1.x - v0.x, d1 = v1.y - v0.y, d2 = v1.z - v0.z, d3 = v1.w - v0.w;
        zwl_acc += d0 * d0 + d1 * d1 + d2 * d2 + d3 * d3;
        n0sq += v0.x * v0.x + v0.y * v0.y + v0.z * v0.z + v0.w * v0.w;
        n1sq += v1.x * v1.x + v1.y * v1.y + v1.z * v1.z + v1.w * v1.w;
        pa0[2 * k]     = pk_f16(v0.x, v0.y);
        pa0[2 * k + 1] = pk_f16(v0.z, v0.w);
        pz1[2 * k]     = pk_f16(v1.x, v1.y);
        pz1[2 * k + 1] = pk_f16(v1.z, v1.w);
        pe[2 * k]      = pk_f16(fabsf(v0.x) * p0, fabsf(v0.y) * p0);
        pe[2 * k + 1]  = pk_f16(fabsf(v0.z) * p0, fabsf(v0.w) * p0);
    }
    n0sq += __shfl_xor(n0sq, 1);      // combine halves (xor-1 -> DPP)
    n1sq += __shfl_xor(n1sq, 1);
    const float inv_n0 = 1.0f / fmaxf(sqrtf(n0sq), 1e-5f);

    // ---- stage tiles (b64, conflict-free layout per round-7 measurement)
    uint2* myz   = &s_z1[cell * CW + half * 4];
    uint2* mybuf = &s_buf[cell * CW + half * 4];
    #pragma unroll
    for (int q = 0; q < 4; ++q) {
        myz[q]   = make_uint2(pz1[2 * q], pz1[2 * q + 1]);
        mybuf[q] = make_uint2(pe[2 * q],  pe[2 * q + 1]);
    }
    if (half == 0) {
        s_p1[cell]  = p1;
        s_rn1[cell] = 1.0f / fmaxf(sqrtf(n1sq), 1e-5f);
    }
    __syncthreads();   // A: e, z1, p1, rn1 visible

    const int i = cell >> 4, j = cell & 15;

    // ---- row-max of e (j-1,j,j+1; edges clamp to own: max(x,x)=x)
    uint2 rm2[4];
    {
        const uint2* le = &s_buf[((j > 0)  ? cell - 1 : cell) * CW + half * 4];
        const uint2* re = &s_buf[((j < 15) ? cell + 1 : cell) * CW + half * 4];
        #pragma unroll
        for (int q = 0; q < 4; ++q) {
            uint2 l = le[q], r = re[q];
            rm2[q].x = pkmax(pkmax(pe[2 * q],     l.x), r.x);
            rm2[q].y = pkmax(pkmax(pe[2 * q + 1], l.y), r.y);
        }
    }
    __syncthreads();   // B: all e reads done before overwrite
    #pragma unroll
    for (int q = 0; q < 4; ++q) mybuf[q] = rm2[q];
    __syncthreads();   // C: row-max visible

    // ---- pool: col-max (i-1,i,i+1; edges clamp) + cosine vs |z1|*p1
    float dp = 0.f, na = 0.f;
    {
        const uint2* ub = &s_buf[((i > 0)  ? cell - Gn : cell) * CW + half * 4];
        const uint2* db = &s_buf[((i < 15) ? cell + Gn : cell) * CW + half * 4];
        #pragma unroll
        for (int q = 0; q < 4; ++q) {
            uint2 u = ub[q], d = db[q];
            uint_t m0 = pkmax(pkmax(rm2[q].x, u.x), d.x);
            uint_t m1 = pkmax(pkmax(rm2[q].y, u.y), d.y);
            dp = fdot2(m0, pz1[2 * q]     & 0x7FFF7FFFu, dp);
            dp = fdot2(m1, pz1[2 * q + 1] & 0x7FFF7FFFu, dp);
            na = fdot2(m0, m0, na);
            na = fdot2(m1, m1, na);
        }
    }
    dp += __shfl_xor(dp, 1);
    na += __shfl_xor(na, 1);
    const float dotp = dp * p1;
    const float nbsq = n1sq * p1 * p1;          // exact ||(|z1|*p1)||^2
    float cosv = dotp / fmaxf(sqrtf(na) * sqrtf(nbsq), EPS_POOL);
    float pool_acc = (half == 0) ? (-cosv * 0.5f * (p0 + p1)) : 0.f;

    // ---- objects_loss: 9 wrapped neighbors (jnp.roll)
    float sum_sim = 0.f, max_sim = NEGBIG;
    bool anym = false;
    #pragma unroll
    for (int di = -1; di <= 1; ++di) {
        #pragma unroll
        for (int dj = -1; dj <= 1; ++dj) {
            const int nb = (((i + di) & 15) << 4) | ((j + dj) & 15);
            const uint2* zz = &s_z1[nb * CW + half * 4];
            float dq = 0.f;
            #pragma unroll
            for (int q = 0; q < 4; ++q) {
                uint2 z = zz[q];
                dq = fdot2(pa0[2 * q],     z.x, dq);
                dq = fdot2(pa0[2 * q + 1], z.y, dq);
            }
            dq += __shfl_xor(dq, 1);
            float s = dq * inv_n0 * s_rn1[nb];
            bool m = s_p1[nb] > THRESH_C;
            sum_sim += m ? s : 0.f;
            max_sim = fmaxf(max_sim, m ? s : NEGBIG);
            anym = anym || m;
        }
    }
    const bool det = p0 > THRESH_C;
    float obj_acc = (det && anym && half == 0) ? (sum_sim - ZCMW * max_sim) : 0.f;
    float cnt = (det && half == 0) ? 1.f : 0.f;

    // ---- z_pres_loss (t index covered by blocks with t < T-2)
    float zpl_acc = 0.f;
    if (half == 0 && t < Tn - 2) {
        const size_t zi = cb0 + cell;
        float q0 = z_pres[zi];
        float q1 = z_pres[zi + (size_t)Bn * Nn];
        float q2 = z_pres[zi + 2 * (size_t)Bn * Nn];
        float sim = 1.f - (q2 - q0) * (q2 - q0);
        zpl_acc = sim * ((q2 - q1) * (q2 - q1) + (q0 - q1) * (q0 - q1));
    }

    // ---- block reduction: wave shuffle -> LDS (8 waves)
    float vals[5] = { zwl_acc, zpl_acc, pool_acc, obj_acc, cnt };
    #pragma unroll
    for (int k = 0; k < 5; ++k) {
        float v = vals[k];
        #pragma unroll
        for (int off = 32; off; off >>= 1) v += __shfl_down(v, off);
        if (lane == 0) s_red[wave * 5 + k] = v;
    }
    __syncthreads();

    if (tid == 0) {
        #pragma unroll
        for (int k = 0; k < 5; ++k) {
            float v = 0.f;
            #pragma unroll
            for (int w = 0; w < 8; ++w) v += s_red[w * 5 + k];
            partials[k * NBLK + blockIdx.x] = v;
        }
        __threadfence();                    // release partials
        unsigned prev = atomicAdd(ctr, 1u); // device-scope
        s_last = (prev == NBLK - 1) ? 1 : 0;
    }
    __syncthreads();

    // ---- last block reduces all partials and finalizes (no 2nd launch)
    if (s_last) {
        __threadfence();                    // acquire
        float acc[5] = { 0.f, 0.f, 0.f, 0.f, 0.f };
        for (int idx = tid; idx < NBLK; idx += 512) {
            #pragma unroll
            for (int k = 0; k < 5; ++k) acc[k] += partials[k * NBLK + idx];
        }
        #pragma unroll
        for (int k = 0; k < 5; ++k) {
            float v = acc[k];
            #pragma unroll
            for (int off = 32; off; off >>= 1) v += __shfl_down(v, off);
            if (lane == 0) s_red[wave * 5 + k] = v;
        }
        __syncthreads();
        if (tid == 0) {
            float r[5];
            #pragma unroll
            for (int k = 0; k < 5; ++k) {
                float v = 0.f;
                #pragma unroll
                for (int w = 0; w < 8; ++w) v += s_red[w * 5 + k];
                r[k] = v;
            }
            float bl = base_losses[0] + base_losses[1] + base_losses[2] + base_losses[3];
            float scaling = fminf(1.0f, (float)gstep[0] / 300000.0f);
            out[0] = bl + r[0] * 10.0f + r[1] + r[2] + r[3] * scaling * 10.0f;
            out[1] = r[0];
            out[2] = r[1];
            out[3] = r[2];
            out[4] = r[3];
            out[5] = r[4];
        }
    }
}

extern "C" void kernel_launch(void* const* d_in, const int* in_sizes, int n_in,
                              void* d_out, int out_size, void* d_ws, size_t ws_size,
                              hipStream_t stream) {
    const float* z_what      = (const float*)d_in[0];
    const float* z_pres_prob = (const float*)d_in[1];
    const float* z_pres      = (const float*)d_in[2];
    const float* base_losses = (const float*)d_in[3];
    const int*   gstep       = (const int*)d_in[4];

    float* partials = (float*)d_ws;                       // 5*NBLK floats
    unsigned* ctr   = (unsigned*)(partials + 5 * NBLK);   // 4 bytes

    (void)hipMemsetAsync(ctr, 0, sizeof(unsigned), stream);
    fused_losses<<<dim3(NBLK), dim3(512), 0, stream>>>(
        z_what, z_pres_prob, z_pres, base_losses, gstep,
        partials, ctr, (float*)d_out);
}